// Round 3
// baseline (1052.097 us; speedup 1.0000x reference)
//
#include <hip/hip_runtime.h>

#define HDIM 128
#define GDIM 512   // 4H
#define TSTEPS 512
#define DDIM 12
#define BATCH 1024
#define RROWS 4                  // batch rows per block
#define NBLK (BATCH / RROWS)     // 256 blocks -> 1 per CU
#define NTHR 512                 // 8 waves

typedef _Float16 half8 __attribute__((ext_vector_type(8)));
typedef float f32x4 __attribute__((ext_vector_type(4)));

#define MFMA16 __builtin_amdgcn_mfma_f32_16x16x32_f16

__device__ __forceinline__ float fsig(float x) {
  // sigmoid(x) = 1/(1+exp(-x))
  float t = __expf(-x);
  return __builtin_amdgcn_rcpf(1.0f + t);
}
__device__ __forceinline__ float ftanh_(float x) {
  // tanh(x) = 1 - 2/(exp(2x)+1); saturates correctly via rcp(inf)=0
  float t = __expf(2.0f * x);
  return 1.0f - 2.0f * __builtin_amdgcn_rcpf(t + 1.0f);
}

__device__ __forceinline__ half8 ldfrag8(const float* p) {
  half8 h;
#pragma unroll
  for (int j = 0; j < 8; ++j) h[j] = (_Float16)p[j];
  return h;
}

__global__ __launch_bounds__(NTHR, 2) void lstm_fused_kernel(
    const float* __restrict__ x,
    const float* __restrict__ Wih0, const float* __restrict__ Whh0,
    const float* __restrict__ bih0, const float* __restrict__ bhh0,
    const float* __restrict__ Wih1, const float* __restrict__ Whh1,
    const float* __restrict__ bih1, const float* __restrict__ bhh1,
    const float* __restrict__ W1, const float* __restrict__ b1,
    const float* __restrict__ W2, const float* __restrict__ b2,
    const float* __restrict__ W3, const float* __restrict__ b3,
    float* __restrict__ out)
{
  // LDS: double-buffered h states (f16, swizzled), x chunk, redistribution scratch
  __shared__ _Float16 h1b[2][16 * HDIM];   // 8 KB
  __shared__ _Float16 h2b[2][16 * HDIM];   // 8 KB
  __shared__ _Float16 xsb[8][16 * 32];     // 8 KB  (8 timesteps, rows 0..3 real, d<12 real, d==12 is bias-one)
  __shared__ float rd[8][4][16][4];        // 8 KB  per-wave gate redistribution [wave][gate][col][row]
  __shared__ float z1s[4][64];
  __shared__ float z2s[4][32];

  const int tid = threadIdx.x;
  const int l  = tid & 63;
  const int w  = tid >> 6;          // wave 0..7
  const int fr = l & 15;            // fragment row (A) / gate-col offset (B)
  const int fk = l >> 4;            // k-group 0..3
  const int swzA = (fr & 7) << 3;   // XOR swizzle in f16 elems
  const int c = l & 15;             // redistributed h-col offset
  const int r = l >> 4;             // redistributed batch row 0..3
  const int rowbase = blockIdx.x * RROWS;
  const int hcol = w * 16 + c;
  const int hwidx = (r * HDIM + hcol) ^ (r << 3);  // r<4 so (r&7)==r

  // ---- zero LDS h buffers and x buffer (pad rows/cols must be 0 forever) ----
  {
    _Float16* f1 = &h1b[0][0];
    _Float16* f2 = &h2b[0][0];
    _Float16* f3 = &xsb[0][0];
    for (int i = tid; i < 2 * 16 * HDIM; i += NTHR) { f1[i] = (_Float16)0.0f; f2[i] = (_Float16)0.0f; }
    for (int i = tid; i < 8 * 16 * 32; i += NTHR) f3[i] = (_Float16)0.0f;
  }

  // ---- preload weight fragments into registers (f16) ----
  // wave w owns gate tiles {w, w+8, w+16, w+24}  => tt = gate index (i,f,g,o)
  half8 whh0f[4][4], wih1f[4][4], whh1f[4][4], wih0f[4];
  float bias1f[4];
#pragma unroll
  for (int tt = 0; tt < 4; ++tt) {
    const int gr = (w + tt * 8) * 16 + fr;       // gate row in [0,512)
    const float* pr0 = Whh0 + gr * HDIM;
    const float* pr1 = Wih1 + gr * HDIM;
    const float* pr2 = Whh1 + gr * HDIM;
#pragma unroll
    for (int kt = 0; kt < 4; ++kt) {
      whh0f[tt][kt] = ldfrag8(pr0 + kt * 32 + fk * 8);
      wih1f[tt][kt] = ldfrag8(pr1 + kt * 32 + fk * 8);
      whh1f[tt][kt] = ldfrag8(pr2 + kt * 32 + fk * 8);
    }
    // W_ih0 fragment, K padded 12->32, combined layer-0 bias folded at k==12
    half8 hf;
#pragma unroll
    for (int j = 0; j < 8; ++j) {
      const int k = fk * 8 + j;
      float v = 0.0f;
      if (k < DDIM) v = Wih0[gr * DDIM + k];
      else if (k == DDIM) v = bih0[gr] + bhh0[gr];
      hf[j] = (_Float16)v;
    }
    wih0f[tt] = hf;
    const int gc = tt * HDIM + hcol;
    bias1f[tt] = bih1[gc] + bhh1[gc];
  }

  const f32x4 zf = {0.0f, 0.0f, 0.0f, 0.0f};
  float c0v = 0.0f, c1v = 0.0f;
  int p = 0;

  for (int t = 0; t < TSTEPS; ++t) {
    // ---- restage x chunk (8 timesteps) every 8 steps ----
    if ((t & 7) == 0) {
      if (tid < 384) {
        const int rr = tid / 96, rem = tid % 96;
        const int tts = rem / 12, d = rem % 12;
        const float v = x[(size_t)(rowbase + rr) * (TSTEPS * DDIM) + (size_t)(t + tts) * DDIM + d];
        xsb[tts][(rr * 32 + d) ^ (rr << 3)] = (_Float16)v;
      } else if (tid < 416) {
        const int q = tid - 384;
        const int rr = q >> 3, tts = q & 7;
        xsb[tts][(rr * 32 + DDIM) ^ (rr << 3)] = (_Float16)1.0f;  // bias-one column
      }
      __syncthreads();
    }

    // ================= phase A : layer 0 =================
    half8 xa = *(const half8*)&xsb[t & 7][(fr * 32 + fk * 8) ^ swzA];
    f32x4 a0 = MFMA16(xa, wih0f[0], zf, 0, 0, 0);
    f32x4 a1 = MFMA16(xa, wih0f[1], zf, 0, 0, 0);
    f32x4 a2 = MFMA16(xa, wih0f[2], zf, 0, 0, 0);
    f32x4 a3 = MFMA16(xa, wih0f[3], zf, 0, 0, 0);
#pragma unroll
    for (int kt = 0; kt < 4; ++kt) {
      half8 ha = *(const half8*)&h1b[p][(fr * HDIM + kt * 32 + fk * 8) ^ swzA];
      a0 = MFMA16(ha, whh0f[0][kt], a0, 0, 0, 0);
      a1 = MFMA16(ha, whh0f[1][kt], a1, 0, 0, 0);
      a2 = MFMA16(ha, whh0f[2][kt], a2, 0, 0, 0);
      a3 = MFMA16(ha, whh0f[3][kt], a3, 0, 0, 0);
    }
    // redistribute gates (rows live on lanes 0..15) to all 64 lanes via per-wave LDS
    if (l < 16) {
      *(f32x4*)&rd[w][0][l][0] = a0;
      *(f32x4*)&rd[w][1][l][0] = a1;
      *(f32x4*)&rd[w][2][l][0] = a2;
      *(f32x4*)&rd[w][3][l][0] = a3;
    }
    // same-wave DS ops are in-order; compiler inserts lgkmcnt before use
    {
      const float gi = rd[w][0][c][r];
      const float gf = rd[w][1][c][r];
      const float gg = rd[w][2][c][r];
      const float go = rd[w][3][c][r];
      const float iv = fsig(gi), fv = fsig(gf), gv = ftanh_(gg), ov = fsig(go);
      c0v = fv * c0v + iv * gv;
      const float h1v = ov * ftanh_(c0v);
      h1b[p ^ 1][hwidx] = (_Float16)h1v;
    }
    __syncthreads();  // h1(t) visible; all reads of old buffers done

    // ================= phase B : layer 1 =================
    f32x4 d0, d1, d2, d3;
    {
      const int fo0 = (fr * HDIM + fk * 8) ^ swzA;
      half8 p1 = *(const half8*)&h1b[p ^ 1][fo0];
      half8 p2 = *(const half8*)&h2b[p][fo0];
      d0 = MFMA16(p1, wih1f[0][0], zf, 0, 0, 0);
      d1 = MFMA16(p1, wih1f[1][0], zf, 0, 0, 0);
      d2 = MFMA16(p1, wih1f[2][0], zf, 0, 0, 0);
      d3 = MFMA16(p1, wih1f[3][0], zf, 0, 0, 0);
      d0 = MFMA16(p2, whh1f[0][0], d0, 0, 0, 0);
      d1 = MFMA16(p2, whh1f[1][0], d1, 0, 0, 0);
      d2 = MFMA16(p2, whh1f[2][0], d2, 0, 0, 0);
      d3 = MFMA16(p2, whh1f[3][0], d3, 0, 0, 0);
    }
#pragma unroll
    for (int kt = 1; kt < 4; ++kt) {
      const int fo = (fr * HDIM + kt * 32 + fk * 8) ^ swzA;
      half8 p1 = *(const half8*)&h1b[p ^ 1][fo];
      half8 p2 = *(const half8*)&h2b[p][fo];
      d0 = MFMA16(p1, wih1f[0][kt], d0, 0, 0, 0);
      d1 = MFMA16(p1, wih1f[1][kt], d1, 0, 0, 0);
      d2 = MFMA16(p1, wih1f[2][kt], d2, 0, 0, 0);
      d3 = MFMA16(p1, wih1f[3][kt], d3, 0, 0, 0);
      d0 = MFMA16(p2, whh1f[0][kt], d0, 0, 0, 0);
      d1 = MFMA16(p2, whh1f[1][kt], d1, 0, 0, 0);
      d2 = MFMA16(p2, whh1f[2][kt], d2, 0, 0, 0);
      d3 = MFMA16(p2, whh1f[3][kt], d3, 0, 0, 0);
    }
    if (l < 16) {
      *(f32x4*)&rd[w][0][l][0] = d0;
      *(f32x4*)&rd[w][1][l][0] = d1;
      *(f32x4*)&rd[w][2][l][0] = d2;
      *(f32x4*)&rd[w][3][l][0] = d3;
    }
    {
      const float gi = rd[w][0][c][r] + bias1f[0];
      const float gf = rd[w][1][c][r] + bias1f[1];
      const float gg = rd[w][2][c][r] + bias1f[2];
      const float go = rd[w][3][c][r] + bias1f[3];
      const float iv = fsig(gi), fv = fsig(gf), gv = ftanh_(gg), ov = fsig(go);
      c1v = fv * c1v + iv * gv;
      const float h2v = ov * ftanh_(c1v);
      h2b[p ^ 1][hwidx] = (_Float16)h2v;
    }
    __syncthreads();  // protects old-buffer reads of this step vs next step's writes
    p ^= 1;
  }
  // final h2 is in h2b[p] (p==0 after 512 flips)

  // ================= MLP head =================
  if (tid < 256) {
    const int rr = tid >> 6, j = tid & 63;
    float s = b1[j];
    const float* wrow = W1 + j * HDIM;
#pragma unroll 4
    for (int k = 0; k < HDIM; ++k)
      s += (float)h2b[p][(rr * HDIM + k) ^ (rr << 3)] * wrow[k];
    z1s[rr][j] = fmaxf(s, 0.0f);
  }
  __syncthreads();
  if (tid < 128) {
    const int rr = tid >> 5, j = tid & 31;
    float s = b2[j];
    const float* wrow = W2 + j * 64;
#pragma unroll 4
    for (int k = 0; k < 64; ++k) s += z1s[rr][k] * wrow[k];
    z2s[rr][j] = fmaxf(s, 0.0f);
  }
  __syncthreads();
  if (tid < 8) {
    const int rr = tid >> 1, j = tid & 1;
    float s = b3[j];
    const float* wrow = W3 + j * 32;
#pragma unroll
    for (int k = 0; k < 32; ++k) s += z2s[rr][k] * wrow[k];
    out[(rowbase + rr) * 2 + j] = s;
  }
}

extern "C" void kernel_launch(void* const* d_in, const int* in_sizes, int n_in,
                              void* d_out, int out_size, void* d_ws, size_t ws_size,
                              hipStream_t stream) {
  (void)in_sizes; (void)n_in; (void)out_size; (void)d_ws; (void)ws_size;
  lstm_fused_kernel<<<NBLK, NTHR, 0, stream>>>(
      (const float*)d_in[0],
      (const float*)d_in[1], (const float*)d_in[2],
      (const float*)d_in[3], (const float*)d_in[4],
      (const float*)d_in[5], (const float*)d_in[6],
      (const float*)d_in[7], (const float*)d_in[8],
      (const float*)d_in[9], (const float*)d_in[10],
      (const float*)d_in[11], (const float*)d_in[12],
      (const float*)d_in[13], (const float*)d_in[14],
      (float*)d_out);
}

// Round 6
// 965.374 us; speedup vs baseline: 1.0898x; 1.0898x over previous
//
#include <hip/hip_runtime.h>

#define HDIM 128
#define GDIM 512   // 4H
#define TSTEPS 512
#define DDIM 12
#define BATCH 1024
#define RROWS 4                  // batch rows per block
#define NBLK (BATCH / RROWS)     // 256 blocks -> 1 per CU
#define NTHR 512                 // 8 waves

typedef _Float16 half8 __attribute__((ext_vector_type(8)));
typedef float f32x4 __attribute__((ext_vector_type(4)));

#define MFMA16 __builtin_amdgcn_mfma_f32_16x16x32_f16

__device__ __forceinline__ float fsig(float x) {
  float t = __expf(-x);
  return __builtin_amdgcn_rcpf(1.0f + t);
}
__device__ __forceinline__ float ftanh_(float x) {
  float t = __expf(2.0f * x);
  return 1.0f - 2.0f * __builtin_amdgcn_rcpf(t + 1.0f);
}

__device__ __forceinline__ half8 ldfrag8(const float* p) {
  half8 h;
#pragma unroll
  for (int j = 0; j < 8; ++j) h[j] = (_Float16)p[j];
  return h;
}

// NOTE: __launch_bounds__ with ONLY the block size: the 8-wave block forces a
// 256-VGPR cap (2 waves/SIMD launchability), which fits the ~250-reg register
// plan. The previous (512,2) capped at 128 VGPR -> 110 MB/dispatch of scratch
// spill traffic (observed WRITE_SIZE) and 1052 us.
__global__ __launch_bounds__(NTHR) void lstm_fused_kernel(
    const float* __restrict__ x,
    const float* __restrict__ Wih0, const float* __restrict__ Whh0,
    const float* __restrict__ bih0, const float* __restrict__ bhh0,
    const float* __restrict__ Wih1, const float* __restrict__ Whh1,
    const float* __restrict__ bih1, const float* __restrict__ bhh1,
    const float* __restrict__ W1, const float* __restrict__ b1,
    const float* __restrict__ W2, const float* __restrict__ b2,
    const float* __restrict__ W3, const float* __restrict__ b3,
    float* __restrict__ out)
{
  __shared__ _Float16 h1b[2][16 * HDIM];   // 8 KB
  __shared__ _Float16 h2b[2][16 * HDIM];   // 8 KB
  __shared__ _Float16 xsb[8][16 * 32];     // 8 KB
  __shared__ float rd[8][4][16][4];        // 8 KB  per-wave gate redistribution
  __shared__ _Float16 wih0s[8][4][64][8];  // 32 KB: per-wave Wih0 B-frags (K padded 12->32, bias col @k=12)
  __shared__ float z1s[4][64];
  __shared__ float z2s[4][32];

  const int tid = threadIdx.x;
  const int l  = tid & 63;
  const int w  = tid >> 6;          // wave 0..7
  const int fr = l & 15;            // fragment row (A) / B-col offset
  const int fk = l >> 4;            // k-group 0..3
  const int swzA = (fr & 7) << 3;   // XOR swizzle in f16 elems
  const int c = l & 15;             // redistributed h-col offset
  const int r = l >> 4;             // redistributed batch row 0..3
  const int rowbase = blockIdx.x * RROWS;
  const int hcol = w * 16 + c;
  const int hwidx = (r * HDIM + hcol) ^ (r << 3);

  // ---- zero LDS h buffers and x buffer (pad rows/cols must stay 0) ----
  {
    _Float16* f1 = &h1b[0][0];
    _Float16* f2 = &h2b[0][0];
    _Float16* f3 = &xsb[0][0];
    for (int i = tid; i < 2 * 16 * HDIM; i += NTHR) { f1[i] = (_Float16)0.0f; f2[i] = (_Float16)0.0f; }
    for (int i = tid; i < 8 * 16 * 32; i += NTHR) f3[i] = (_Float16)0.0f;
  }

  // ---- preload weight fragments: Whh0/Wih1/Whh1 in registers (192 VGPR),
  //      Wih0 (with folded layer-0 bias) staged to LDS ----
  half8 whh0f[4][4], wih1f[4][4], whh1f[4][4];
  float bias1f[4];
#pragma unroll
  for (int tt = 0; tt < 4; ++tt) {
    const int gr = (w + tt * 8) * 16 + fr;       // gate row in [0,512)
    const float* pr0 = Whh0 + gr * HDIM;
    const float* pr1 = Wih1 + gr * HDIM;
    const float* pr2 = Whh1 + gr * HDIM;
#pragma unroll
    for (int kt = 0; kt < 4; ++kt) {
      whh0f[tt][kt] = ldfrag8(pr0 + kt * 32 + fk * 8);
      wih1f[tt][kt] = ldfrag8(pr1 + kt * 32 + fk * 8);
      whh1f[tt][kt] = ldfrag8(pr2 + kt * 32 + fk * 8);
    }
    half8 hf;
#pragma unroll
    for (int j = 0; j < 8; ++j) {
      const int k = fk * 8 + j;
      float v = 0.0f;
      if (k < DDIM) v = Wih0[gr * DDIM + k];
      else if (k == DDIM) v = bih0[gr] + bhh0[gr];
      hf[j] = (_Float16)v;
    }
    *(half8*)&wih0s[w][tt][l][0] = hf;
    const int gc = tt * HDIM + hcol;
    bias1f[tt] = bih1[gc] + bhh1[gc];
  }

  const f32x4 zf = {0.0f, 0.0f, 0.0f, 0.0f};
  float c0v = 0.0f, c1v = 0.0f;
  int p = 0;

  for (int t = 0; t < TSTEPS; ++t) {
    // ---- restage x chunk (8 timesteps) every 8 steps ----
    // Safe without a leading barrier: xsb is only read in phase A, and all
    // phase-A reads of the previous chunk completed before B1 of step t-1.
    if ((t & 7) == 0) {
      if (tid < 384) {
        const int rr = tid / 96, rem = tid % 96;
        const int tts = rem / 12, d = rem % 12;
        const float v = x[(size_t)(rowbase + rr) * (TSTEPS * DDIM) + (size_t)(t + tts) * DDIM + d];
        xsb[tts][(rr * 32 + d) ^ (rr << 3)] = (_Float16)v;
      } else if (tid < 416) {
        const int q = tid - 384;
        const int rr = q >> 3, tts = q & 7;
        xsb[tts][(rr * 32 + DDIM) ^ (rr << 3)] = (_Float16)1.0f;  // bias-one col
      }
      __syncthreads();
    }

    // ================= phase A : layer 0 =================
    half8 xa = *(const half8*)&xsb[t & 7][(fr * 32 + fk * 8) ^ swzA];
    f32x4 a0, a1, a2, a3;
    {
      half8 w0 = *(const half8*)&wih0s[w][0][l][0];
      half8 w1 = *(const half8*)&wih0s[w][1][l][0];
      half8 w2 = *(const half8*)&wih0s[w][2][l][0];
      half8 w3 = *(const half8*)&wih0s[w][3][l][0];
      a0 = MFMA16(xa, w0, zf, 0, 0, 0);
      a1 = MFMA16(xa, w1, zf, 0, 0, 0);
      a2 = MFMA16(xa, w2, zf, 0, 0, 0);
      a3 = MFMA16(xa, w3, zf, 0, 0, 0);
    }
#pragma unroll
    for (int kt = 0; kt < 4; ++kt) {
      half8 ha = *(const half8*)&h1b[p][(fr * HDIM + kt * 32 + fk * 8) ^ swzA];
      a0 = MFMA16(ha, whh0f[0][kt], a0, 0, 0, 0);
      a1 = MFMA16(ha, whh0f[1][kt], a1, 0, 0, 0);
      a2 = MFMA16(ha, whh0f[2][kt], a2, 0, 0, 0);
      a3 = MFMA16(ha, whh0f[3][kt], a3, 0, 0, 0);
    }
    if (l < 16) {
      *(f32x4*)&rd[w][0][l][0] = a0;
      *(f32x4*)&rd[w][1][l][0] = a1;
      *(f32x4*)&rd[w][2][l][0] = a2;
      *(f32x4*)&rd[w][3][l][0] = a3;
    }
    {
      const float gi = rd[w][0][c][r];
      const float gf = rd[w][1][c][r];
      const float gg = rd[w][2][c][r];
      const float go = rd[w][3][c][r];
      const float iv = fsig(gi), fv = fsig(gf), gv = ftanh_(gg), ov = fsig(go);
      c0v = fv * c0v + iv * gv;
      const float h1v = ov * ftanh_(c0v);
      h1b[p ^ 1][hwidx] = (_Float16)h1v;
    }
    __syncthreads();  // B1: h1(t) visible; sole barrier per step (B2 proven redundant)

    // ================= phase B : layer 1 =================
    f32x4 d0, d1, d2, d3;
    {
      const int fo0 = (fr * HDIM + fk * 8) ^ swzA;
      half8 p1 = *(const half8*)&h1b[p ^ 1][fo0];
      half8 p2 = *(const half8*)&h2b[p][fo0];
      d0 = MFMA16(p1, wih1f[0][0], zf, 0, 0, 0);
      d1 = MFMA16(p1, wih1f[1][0], zf, 0, 0, 0);
      d2 = MFMA16(p1, wih1f[2][0], zf, 0, 0, 0);
      d3 = MFMA16(p1, wih1f[3][0], zf, 0, 0, 0);
      d0 = MFMA16(p2, whh1f[0][0], d0, 0, 0, 0);
      d1 = MFMA16(p2, whh1f[1][0], d1, 0, 0, 0);
      d2 = MFMA16(p2, whh1f[2][0], d2, 0, 0, 0);
      d3 = MFMA16(p2, whh1f[3][0], d3, 0, 0, 0);
    }
#pragma unroll
    for (int kt = 1; kt < 4; ++kt) {
      const int fo = (fr * HDIM + kt * 32 + fk * 8) ^ swzA;
      half8 p1 = *(const half8*)&h1b[p ^ 1][fo];
      half8 p2 = *(const half8*)&h2b[p][fo];
      d0 = MFMA16(p1, wih1f[0][kt], d0, 0, 0, 0);
      d1 = MFMA16(p1, wih1f[1][kt], d1, 0, 0, 0);
      d2 = MFMA16(p1, wih1f[2][kt], d2, 0, 0, 0);
      d3 = MFMA16(p1, wih1f[3][kt], d3, 0, 0, 0);
      d0 = MFMA16(p2, whh1f[0][kt], d0, 0, 0, 0);
      d1 = MFMA16(p2, whh1f[1][kt], d1, 0, 0, 0);
      d2 = MFMA16(p2, whh1f[2][kt], d2, 0, 0, 0);
      d3 = MFMA16(p2, whh1f[3][kt], d3, 0, 0, 0);
    }
    if (l < 16) {
      *(f32x4*)&rd[w][0][l][0] = d0;
      *(f32x4*)&rd[w][1][l][0] = d1;
      *(f32x4*)&rd[w][2][l][0] = d2;
      *(f32x4*)&rd[w][3][l][0] = d3;
    }
    {
      const float gi = rd[w][0][c][r] + bias1f[0];
      const float gf = rd[w][1][c][r] + bias1f[1];
      const float gg = rd[w][2][c][r] + bias1f[2];
      const float go = rd[w][3][c][r] + bias1f[3];
      const float iv = fsig(gi), fv = fsig(gf), gv = ftanh_(gg), ov = fsig(go);
      c1v = fv * c1v + iv * gv;
      const float h2v = ov * ftanh_(c1v);
      h2b[p ^ 1][hwidx] = (_Float16)h2v;
    }
    // no second barrier: phaseA(t+1) touches h1b[p]/xsb only (reads all pre-B1);
    // h2b[p^1] readers are in phaseB(t+1), ordered by B1(t+1).
    p ^= 1;
  }

  __syncthreads();  // h2b[p] writes visible for the MLP head

  // ================= MLP head =================
  if (tid < 256) {
    const int rr = tid >> 6, j = tid & 63;
    float s = b1[j];
    const float* wrow = W1 + j * HDIM;
#pragma unroll 4
    for (int k = 0; k < HDIM; ++k)
      s += (float)h2b[p][(rr * HDIM + k) ^ (rr << 3)] * wrow[k];
    z1s[rr][j] = fmaxf(s, 0.0f);
  }
  __syncthreads();
  if (tid < 128) {
    const int rr = tid >> 5, j = tid & 31;
    float s = b2[j];
    const float* wrow = W2 + j * 64;
#pragma unroll 4
    for (int k = 0; k < 64; ++k) s += z1s[rr][k] * wrow[k];
    z2s[rr][j] = fmaxf(s, 0.0f);
  }
  __syncthreads();
  if (tid < 8) {
    const int rr = tid >> 1, j = tid & 1;
    float s = b3[j];
    const float* wrow = W3 + j * 32;
#pragma unroll
    for (int k = 0; k < 32; ++k) s += z2s[rr][k] * wrow[k];
    out[(rowbase + rr) * 2 + j] = s;
  }
}

extern "C" void kernel_launch(void* const* d_in, const int* in_sizes, int n_in,
                              void* d_out, int out_size, void* d_ws, size_t ws_size,
                              hipStream_t stream) {
  (void)in_sizes; (void)n_in; (void)out_size; (void)d_ws; (void)ws_size;
  lstm_fused_kernel<<<NBLK, NTHR, 0, stream>>>(
      (const float*)d_in[0],
      (const float*)d_in[1], (const float*)d_in[2],
      (const float*)d_in[3], (const float*)d_in[4],
      (const float*)d_in[5], (const float*)d_in[6],
      (const float*)d_in[7], (const float*)d_in[8],
      (const float*)d_in[9], (const float*)d_in[10],
      (const float*)d_in[11], (const float*)d_in[12],
      (const float*)d_in[13], (const float*)d_in[14],
      (float*)d_out);
}

// Round 12
// 962.903 us; speedup vs baseline: 1.0926x; 1.0026x over previous
//
#include <hip/hip_runtime.h>

#define HDIM 128
#define GDIM 512   // 4H
#define TSTEPS 512
#define DDIM 12
#define BATCH 1024
#define RROWS 4                  // batch rows per block
#define NBLK (BATCH / RROWS)     // 256 blocks -> 1 per CU
#define NTHR 512                 // 8 waves

typedef _Float16 half8 __attribute__((ext_vector_type(8)));
typedef float f32x4 __attribute__((ext_vector_type(4)));

#define MFMA16 __builtin_amdgcn_mfma_f32_16x16x32_f16

__device__ __forceinline__ float fsig(float x) {
  float t = __expf(-x);
  return __builtin_amdgcn_rcpf(1.0f + t);
}
__device__ __forceinline__ float ftanh_(float x) {
  float t = __expf(2.0f * x);
  return 1.0f - 2.0f * __builtin_amdgcn_rcpf(t + 1.0f);
}

__device__ __forceinline__ half8 ldfrag8(const float* p) {
  half8 h;
#pragma unroll
  for (int j = 0; j < 8; ++j) h[j] = (_Float16)p[j];
  return h;
}

// amdgpu_waves_per_eu(2,2): pins BOTH min and max occupancy to 2 waves/EU
// (forced anyway by the 8-wave block), unlocking the full 256-VGPR budget.
// __launch_bounds__(512[,2]) alone left the allocator's occupancy heuristic
// free to target 4 waves/EU -> 128-VGPR cap -> ~88 MB/dispatch spill traffic
// (observed WRITE_SIZE in rounds 3+6) and ~4500 cy/step vs ~520 cy MFMA floor.
// Weights MUST live in registers: 3 matrices x 512x128 x fp16 = 384 KB/CU,
// > 160 KB LDS, and > the 256 KB register file available at a 128-VGPR cap.
__global__ __launch_bounds__(NTHR)
__attribute__((amdgpu_waves_per_eu(2, 2)))
void lstm_fused_kernel(
    const float* __restrict__ x,
    const float* __restrict__ Wih0, const float* __restrict__ Whh0,
    const float* __restrict__ bih0, const float* __restrict__ bhh0,
    const float* __restrict__ Wih1, const float* __restrict__ Whh1,
    const float* __restrict__ bih1, const float* __restrict__ bhh1,
    const float* __restrict__ W1, const float* __restrict__ b1,
    const float* __restrict__ W2, const float* __restrict__ b2,
    const float* __restrict__ W3, const float* __restrict__ b3,
    float* __restrict__ out)
{
  __shared__ _Float16 h1b[2][16 * HDIM];   // 8 KB
  __shared__ _Float16 h2b[2][16 * HDIM];   // 8 KB
  __shared__ _Float16 xsb[8][16 * 32];     // 8 KB
  __shared__ float rd[8][4][16][4];        // 8 KB  per-wave gate redistribution
  __shared__ _Float16 wih0s[8][4][64][8];  // 32 KB: per-wave Wih0 B-frags (K padded 12->32, bias col @k=12)
  __shared__ float z1s[4][64];
  __shared__ float z2s[4][32];

  const int tid = threadIdx.x;
  const int l  = tid & 63;
  const int w  = tid >> 6;          // wave 0..7
  const int fr = l & 15;            // fragment row (A) / B-col offset
  const int fk = l >> 4;            // k-group 0..3
  const int swzA = (fr & 7) << 3;   // XOR swizzle in f16 elems
  const int c = l & 15;             // redistributed h-col offset
  const int r = l >> 4;             // redistributed batch row 0..3
  const int rowbase = blockIdx.x * RROWS;
  const int hcol = w * 16 + c;
  const int hwidx = (r * HDIM + hcol) ^ (r << 3);

  // ---- zero LDS h buffers and x buffer (pad rows/cols must stay 0) ----
  {
    _Float16* f1 = &h1b[0][0];
    _Float16* f2 = &h2b[0][0];
    _Float16* f3 = &xsb[0][0];
    for (int i = tid; i < 2 * 16 * HDIM; i += NTHR) { f1[i] = (_Float16)0.0f; f2[i] = (_Float16)0.0f; }
    for (int i = tid; i < 8 * 16 * 32; i += NTHR) f3[i] = (_Float16)0.0f;
  }

  // ---- preload weight fragments: Whh0/Wih1/Whh1 in registers (192 VGPR),
  //      Wih0 (with folded layer-0 bias) staged to LDS ----
  half8 whh0f[4][4], wih1f[4][4], whh1f[4][4];
  float bias1f[4];
#pragma unroll
  for (int tt = 0; tt < 4; ++tt) {
    const int gr = (w + tt * 8) * 16 + fr;       // gate row in [0,512)
    const float* pr0 = Whh0 + gr * HDIM;
    const float* pr1 = Wih1 + gr * HDIM;
    const float* pr2 = Whh1 + gr * HDIM;
#pragma unroll
    for (int kt = 0; kt < 4; ++kt) {
      whh0f[tt][kt] = ldfrag8(pr0 + kt * 32 + fk * 8);
      wih1f[tt][kt] = ldfrag8(pr1 + kt * 32 + fk * 8);
      whh1f[tt][kt] = ldfrag8(pr2 + kt * 32 + fk * 8);
    }
    half8 hf;
#pragma unroll
    for (int j = 0; j < 8; ++j) {
      const int k = fk * 8 + j;
      float v = 0.0f;
      if (k < DDIM) v = Wih0[gr * DDIM + k];
      else if (k == DDIM) v = bih0[gr] + bhh0[gr];
      hf[j] = (_Float16)v;
    }
    *(half8*)&wih0s[w][tt][l][0] = hf;
    const int gc = tt * HDIM + hcol;
    bias1f[tt] = bih1[gc] + bhh1[gc];
  }

  const f32x4 zf = {0.0f, 0.0f, 0.0f, 0.0f};
  float c0v = 0.0f, c1v = 0.0f;
  int p = 0;

  for (int t = 0; t < TSTEPS; ++t) {
    // ---- restage x chunk (8 timesteps) every 8 steps ----
    if ((t & 7) == 0) {
      if (tid < 384) {
        const int rr = tid / 96, rem = tid % 96;
        const int tts = rem / 12, d = rem % 12;
        const float v = x[(size_t)(rowbase + rr) * (TSTEPS * DDIM) + (size_t)(t + tts) * DDIM + d];
        xsb[tts][(rr * 32 + d) ^ (rr << 3)] = (_Float16)v;
      } else if (tid < 416) {
        const int q = tid - 384;
        const int rr = q >> 3, tts = q & 7;
        xsb[tts][(rr * 32 + DDIM) ^ (rr << 3)] = (_Float16)1.0f;  // bias-one col
      }
      __syncthreads();
    }

    // ================= phase A : layer 0 =================
    half8 xa = *(const half8*)&xsb[t & 7][(fr * 32 + fk * 8) ^ swzA];
    f32x4 a0, a1, a2, a3;
    {
      half8 w0 = *(const half8*)&wih0s[w][0][l][0];
      half8 w1 = *(const half8*)&wih0s[w][1][l][0];
      half8 w2 = *(const half8*)&wih0s[w][2][l][0];
      half8 w3 = *(const half8*)&wih0s[w][3][l][0];
      a0 = MFMA16(xa, w0, zf, 0, 0, 0);
      a1 = MFMA16(xa, w1, zf, 0, 0, 0);
      a2 = MFMA16(xa, w2, zf, 0, 0, 0);
      a3 = MFMA16(xa, w3, zf, 0, 0, 0);
    }
#pragma unroll
    for (int kt = 0; kt < 4; ++kt) {
      half8 ha = *(const half8*)&h1b[p][(fr * HDIM + kt * 32 + fk * 8) ^ swzA];
      a0 = MFMA16(ha, whh0f[0][kt], a0, 0, 0, 0);
      a1 = MFMA16(ha, whh0f[1][kt], a1, 0, 0, 0);
      a2 = MFMA16(ha, whh0f[2][kt], a2, 0, 0, 0);
      a3 = MFMA16(ha, whh0f[3][kt], a3, 0, 0, 0);
    }
    if (l < 16) {
      *(f32x4*)&rd[w][0][l][0] = a0;
      *(f32x4*)&rd[w][1][l][0] = a1;
      *(f32x4*)&rd[w][2][l][0] = a2;
      *(f32x4*)&rd[w][3][l][0] = a3;
    }
    {
      const float gi = rd[w][0][c][r];
      const float gf = rd[w][1][c][r];
      const float gg = rd[w][2][c][r];
      const float go = rd[w][3][c][r];
      const float iv = fsig(gi), fv = fsig(gf), gv = ftanh_(gg), ov = fsig(go);
      c0v = fv * c0v + iv * gv;
      const float h1v = ov * ftanh_(c0v);
      h1b[p ^ 1][hwidx] = (_Float16)h1v;
    }
    __syncthreads();  // B1: h1(t) visible; sole barrier per step

    // ================= phase B : layer 1 =================
    f32x4 d0, d1, d2, d3;
    {
      const int fo0 = (fr * HDIM + fk * 8) ^ swzA;
      half8 p1 = *(const half8*)&h1b[p ^ 1][fo0];
      half8 p2 = *(const half8*)&h2b[p][fo0];
      d0 = MFMA16(p1, wih1f[0][0], zf, 0, 0, 0);
      d1 = MFMA16(p1, wih1f[1][0], zf, 0, 0, 0);
      d2 = MFMA16(p1, wih1f[2][0], zf, 0, 0, 0);
      d3 = MFMA16(p1, wih1f[3][0], zf, 0, 0, 0);
      d0 = MFMA16(p2, whh1f[0][0], d0, 0, 0, 0);
      d1 = MFMA16(p2, whh1f[1][0], d1, 0, 0, 0);
      d2 = MFMA16(p2, whh1f[2][0], d2, 0, 0, 0);
      d3 = MFMA16(p2, whh1f[3][0], d3, 0, 0, 0);
    }
#pragma unroll
    for (int kt = 1; kt < 4; ++kt) {
      const int fo = (fr * HDIM + kt * 32 + fk * 8) ^ swzA;
      half8 p1 = *(const half8*)&h1b[p ^ 1][fo];
      half8 p2 = *(const half8*)&h2b[p][fo];
      d0 = MFMA16(p1, wih1f[0][kt], d0, 0, 0, 0);
      d1 = MFMA16(p1, wih1f[1][kt], d1, 0, 0, 0);
      d2 = MFMA16(p1, wih1f[2][kt], d2, 0, 0, 0);
      d3 = MFMA16(p1, wih1f[3][kt], d3, 0, 0, 0);
      d0 = MFMA16(p2, whh1f[0][kt], d0, 0, 0, 0);
      d1 = MFMA16(p2, whh1f[1][kt], d1, 0, 0, 0);
      d2 = MFMA16(p2, whh1f[2][kt], d2, 0, 0, 0);
      d3 = MFMA16(p2, whh1f[3][kt], d3, 0, 0, 0);
    }
    if (l < 16) {
      *(f32x4*)&rd[w][0][l][0] = d0;
      *(f32x4*)&rd[w][1][l][0] = d1;
      *(f32x4*)&rd[w][2][l][0] = d2;
      *(f32x4*)&rd[w][3][l][0] = d3;
    }
    {
      const float gi = rd[w][0][c][r] + bias1f[0];
      const float gf = rd[w][1][c][r] + bias1f[1];
      const float gg = rd[w][2][c][r] + bias1f[2];
      const float go = rd[w][3][c][r] + bias1f[3];
      const float iv = fsig(gi), fv = fsig(gf), gv = ftanh_(gg), ov = fsig(go);
      c1v = fv * c1v + iv * gv;
      const float h2v = ov * ftanh_(c1v);
      h2b[p ^ 1][hwidx] = (_Float16)h2v;
    }
    // no second barrier: phaseA(t+1) touches h1b[p]/xsb only (reads all pre-B1);
    // h2b[p^1] readers are in phaseB(t+1), ordered by B1(t+1).
    p ^= 1;
  }

  __syncthreads();  // h2b[p] writes visible for the MLP head

  // ================= MLP head =================
  if (tid < 256) {
    const int rr = tid >> 6, j = tid & 63;
    float s = b1[j];
    const float* wrow = W1 + j * HDIM;
#pragma unroll 4
    for (int k = 0; k < HDIM; ++k)
      s += (float)h2b[p][(rr * HDIM + k) ^ (rr << 3)] * wrow[k];
    z1s[rr][j] = fmaxf(s, 0.0f);
  }
  __syncthreads();
  if (tid < 128) {
    const int rr = tid >> 5, j = tid & 31;
    float s = b2[j];
    const float* wrow = W2 + j * 64;
#pragma unroll 4
    for (int k = 0; k < 64; ++k) s += z1s[rr][k] * wrow[k];
    z2s[rr][j] = fmaxf(s, 0.0f);
  }
  __syncthreads();
  if (tid < 8) {
    const int rr = tid >> 1, j = tid & 1;
    float s = b3[j];
    const float* wrow = W3 + j * 32;
#pragma unroll
    for (int k = 0; k < 32; ++k) s += z2s[rr][k] * wrow[k];
    out[(rowbase + rr) * 2 + j] = s;
  }
}

extern "C" void kernel_launch(void* const* d_in, const int* in_sizes, int n_in,
                              void* d_out, int out_size, void* d_ws, size_t ws_size,
                              hipStream_t stream) {
  (void)in_sizes; (void)n_in; (void)out_size; (void)d_ws; (void)ws_size;
  lstm_fused_kernel<<<NBLK, NTHR, 0, stream>>>(
      (const float*)d_in[0],
      (const float*)d_in[1], (const float*)d_in[2],
      (const float*)d_in[3], (const float*)d_in[4],
      (const float*)d_in[5], (const float*)d_in[6],
      (const float*)d_in[7], (const float*)d_in[8],
      (const float*)d_in[9], (const float*)d_in[10],
      (const float*)d_in[11], (const float*)d_in[12],
      (const float*)d_in[13], (const float*)d_in[14],
      (float*)d_out);
}